// Round 2
// baseline (15921.930 us; speedup 1.0000x reference)
//
#include <hip/hip_runtime.h>
#include <hip/hip_bf16.h>

#define KD 128
#define HDD 512
#define BB 64
#define NE 512
#define NC 3584  // 7*HDD

// d_out element offsets (fp32 outputs concatenated flat in return order)
#define LAMB_OFF  0UL
#define CLOW_OFF  4194304UL    // B*N*K
#define CBAR_OFF  20971520UL   // + B*N*HD
#define DELTA_OFF 37748736UL
#define OGATE_OFF 54525952UL

__device__ __forceinline__ float sigf(float x) { return 1.0f / (1.0f + expf(-x)); }

// ---------------- pre-pass kernels ----------------

// one block per (b,t) row; find the index of the 1.0 in the one-hot
__global__ void marks_k(const float* __restrict__ seq, int* __restrict__ marks) {
    int row = blockIdx.x;       // b*NE + t
    int k = threadIdx.x;        // 0..127
    float v = seq[(size_t)row * KD + k];
    if (v > 0.5f) marks[row] = k;
}

// tiled transpose: dst[c*R + r] = src[r*C + c]
__global__ void transpose_k(const float* __restrict__ src, float* __restrict__ dst,
                            int R, int C) {
    __shared__ float tile[32][33];
    int tx = threadIdx.x & 31, ty = threadIdx.x >> 5;   // 256 threads: 32x8
    int c0 = blockIdx.x * 32, r0 = blockIdx.y * 32;
    for (int i = ty; i < 32; i += 8) {
        int r = r0 + i, c = c0 + tx;
        if (r < R && c < C) tile[i][tx] = src[(size_t)r * C + c];
    }
    __syncthreads();
    for (int i = ty; i < 32; i += 8) {
        int c = c0 + i, r = r0 + tx;
        if (r < R && c < C) dst[(size_t)c * R + r] = tile[tx][i];
    }
}

// ---------------- lamb (intensity) ----------------

__device__ __forceinline__ void lamb_body(const float* __restrict__ h,
                                          const float* __restrict__ Wlamb,
                                          const float* __restrict__ blamb,
                                          const float* __restrict__ scale,
                                          float* __restrict__ out,
                                          int tprev, int b, int kk) {
    float acc = 0.0f;
    for (int k0 = 0; k0 < HDD; k0 += 4) {
#pragma unroll
        for (int u = 0; u < 4; ++u)
            acc += h[(k0 + u) * BB + b] * Wlamb[(size_t)(k0 + u) * KD + kk];
    }
    float lt = acc + blamb[kk];
    float sc = scale[kk];
    float s  = lt / sc;
    float sp = (s > 20.0f) ? s : log1pf(expf(s));
    float lam = sc * sp;
    out[LAMB_OFF + ((size_t)b * NE + tprev) * KD + kk] = lam;
}

// ---------------- per-step kernel ----------------
// blocks 0..255: state update for hidden units j = 2*wg, 2*wg+1 (all 64 batches)
// blocks 256..287: lamb for step t-1 (pipelined; skipped at t=0)
__global__ void __launch_bounds__(256) step_k(
    const float* __restrict__ Wvt,    // [3584][512]  (transposed W_V)
    const float* __restrict__ Wut,    // [3584][128]  (transposed W_U)
    const float* __restrict__ bU, const float* __restrict__ bV,
    const float* __restrict__ Wlamb,  // [512][128]
    const float* __restrict__ blamb, const float* __restrict__ scale,
    const float* __restrict__ times,  // [B][513]
    const int* __restrict__ marks,    // [B][512]
    const float* __restrict__ h_in,   // [512][64]
    float* __restrict__ h_out,        // [512][64]
    float* __restrict__ ct, float* __restrict__ cbar,   // [512][64]
    float* __restrict__ out, int t)
{
    int wg  = blockIdx.x;
    int tid = threadIdx.x;
    int b   = tid & 63;

    if (wg < 256) {
        __shared__ float gv[7][2][64];
        int sub = tid >> 6;          // 0..3
        int jl  = sub & 1;
        int gh  = sub >> 1;          // 0: gates 0..3, 1: gates 4..6
        int j   = (wg << 1) + jl;
        int g0  = gh ? 4 : 0;
        int ng  = gh ? 3 : 4;
        int mk  = marks[b * NE + t];

        const float* wrow[4];
#pragma unroll
        for (int g = 0; g < 4; ++g) {
            int gg = g0 + ((g < ng) ? g : 0);   // dup row for the unused slot
            wrow[g] = Wvt + ((size_t)gg * HDD + j) * HDD;
        }

        float acc0 = 0.f, acc1 = 0.f, acc2 = 0.f, acc3 = 0.f;
        for (int k0 = 0; k0 < HDD; k0 += 4) {
            float h0v = h_in[(k0 + 0) * BB + b];
            float h1v = h_in[(k0 + 1) * BB + b];
            float h2v = h_in[(k0 + 2) * BB + b];
            float h3v = h_in[(k0 + 3) * BB + b];
            float4 wa = *reinterpret_cast<const float4*>(wrow[0] + k0);
            float4 wb = *reinterpret_cast<const float4*>(wrow[1] + k0);
            float4 wc = *reinterpret_cast<const float4*>(wrow[2] + k0);
            float4 wd = *reinterpret_cast<const float4*>(wrow[3] + k0);
            acc0 += h0v * wa.x + h1v * wa.y + h2v * wa.z + h3v * wa.w;
            acc1 += h0v * wb.x + h1v * wb.y + h2v * wb.z + h3v * wb.w;
            acc2 += h0v * wc.x + h1v * wc.y + h2v * wc.z + h3v * wc.w;
            acc3 += h0v * wd.x + h1v * wd.y + h2v * wd.z + h3v * wd.w;
        }

        float accs[4] = {acc0, acc1, acc2, acc3};
#pragma unroll
        for (int g = 0; g < 4; ++g) {
            if (g < ng) {
                int c = (g0 + g) * HDD + j;
                float a = accs[g] + bU[c] + bV[c] + Wut[(size_t)c * KD + mk];
                gv[g0 + g][jl][b] = a;
            }
        }
        __syncthreads();

        if (tid < 128) {
            int jl2 = tid >> 6;
            int jj  = (wg << 1) + jl2;
            float gi  = gv[0][jl2][b], gf  = gv[1][jl2][b];
            float gib = gv[2][jl2][b], gfb = gv[3][jl2][b];
            float gz  = gv[4][jl2][b], go  = gv[5][jl2][b];
            float gd  = gv[6][jl2][b];

            float iv  = sigf(gi),  fv  = sigf(gf);
            float ibv = sigf(gib), fbv = sigf(gfb);
            float zv  = 2.0f * sigf(gz);
            float ov  = sigf(go);
            float dv  = (gd > 0.0f) ? gd : 0.01f * gd;

            int sidx = jj * BB + b;
            float ctv = ct[sidx], cbv = cbar[sidx];
            float clow = fv * ctv + iv * zv;
            float cbn  = fbv * cbv + ibv * zv;
            float dt   = times[b * (NE + 1) + t + 1] - times[b * (NE + 1) + t];
            float ctn  = cbn + (clow - cbn) * expf(dt * dv);
            float th   = 2.0f * sigf(2.0f * ctn) - 1.0f;   // tanh(ctn), same formula as ref
            float hn   = ov * th;

            ct[sidx]   = ctn;
            cbar[sidx] = cbn;
            h_out[sidx] = hn;

            size_t ob = ((size_t)b * NE + t) * HDD + jj;
            out[CLOW_OFF  + ob] = clow;
            out[CBAR_OFF  + ob] = cbn;
            out[DELTA_OFF + ob] = dv;
            out[OGATE_OFF + ob] = ov;
        }
    } else {
        if (t == 0) return;
        int wg2 = wg - 256;          // 0..31
        int kl  = tid >> 6;          // 0..3
        int kk  = (wg2 << 2) + kl;   // 0..127
        lamb_body(h_in, Wlamb, blamb, scale, out, t - 1, b, kk);
    }
}

__global__ void __launch_bounds__(256) lamb_fin_k(
    const float* __restrict__ h, const float* __restrict__ Wlamb,
    const float* __restrict__ blamb, const float* __restrict__ scale,
    float* __restrict__ out)
{
    int b  = threadIdx.x & 63;
    int kl = threadIdx.x >> 6;
    int kk = (blockIdx.x << 2) + kl;
    lamb_body(h, Wlamb, blamb, scale, out, NE - 1, b, kk);
}

// ---------------- launcher ----------------

extern "C" void kernel_launch(void* const* d_in, const int* in_sizes, int n_in,
                              void* d_out, int out_size, void* d_ws, size_t ws_size,
                              hipStream_t stream)
{
    const float* seq    = (const float*)d_in[0];
    const float* times  = (const float*)d_in[1];
    const float* W_U    = (const float*)d_in[2];
    const float* b_U    = (const float*)d_in[3];
    const float* W_V    = (const float*)d_in[4];
    const float* b_V    = (const float*)d_in[5];
    const float* W_lamb = (const float*)d_in[6];
    const float* b_lamb = (const float*)d_in[7];
    const float* scale  = (const float*)d_in[8];
    float* out = (float*)d_out;

    float* ws  = (float*)d_ws;
    float* Wvt = ws;                        // 3584*512
    float* Wut = Wvt + (size_t)NC * HDD;    // 3584*128
    float* h0  = Wut + (size_t)NC * KD;     // 512*64
    float* ctb = h0  + HDD * BB;            // 512*64
    float* cbb = ctb + HDD * BB;            // 512*64
    float* h1  = cbb + HDD * BB;            // 512*64
    int* marks = (int*)(h1 + HDD * BB);     // 64*512 ints

    // zero h0, ct, cbar (contiguous); h1 is fully written at t=0 before first read
    hipMemsetAsync(h0, 0, (size_t)3 * HDD * BB * sizeof(float), stream);

    marks_k<<<BB * NE, KD, 0, stream>>>(seq, marks);
    transpose_k<<<dim3(NC / 32, HDD / 32), 256, 0, stream>>>(W_V, Wvt, HDD, NC);
    transpose_k<<<dim3(NC / 32, KD / 32),  256, 0, stream>>>(W_U, Wut, KD, NC);

    for (int t = 0; t < NE; ++t) {
        float* hin  = (t & 1) ? h1 : h0;
        float* hout = (t & 1) ? h0 : h1;
        step_k<<<288, 256, 0, stream>>>(Wvt, Wut, b_U, b_V, W_lamb, b_lamb, scale,
                                        times, marks, hin, hout, ctb, cbb, out, t);
    }
    // after t=511 (odd), final h lives in h0
    lamb_fin_k<<<32, 256, 0, stream>>>(h0, W_lamb, b_lamb, scale, out);
}